// Round 5
// baseline (464.956 us; speedup 1.0000x reference)
//
#include <hip/hip_runtime.h>
#include <math.h>

typedef unsigned int uint;
typedef unsigned short ushort;

__device__ inline ushort f2bf(float f) {
    uint u = __float_as_uint(f);
    u += 0x7FFF + ((u >> 16) & 1);  // round-to-nearest-even
    return (ushort)(u >> 16);
}
__device__ inline float bf2f(ushort s) {
    return __uint_as_float(((uint)s) << 16);
}

// ---- GEMM1: h1b[N,64](bf16) = x[N,128] @ W1[128,64], fused al1s/al1d ----
__global__ __launch_bounds__(256) void k_gemm1(const float* __restrict__ x,
                                               const float* __restrict__ W1,
                                               const float* __restrict__ as1,
                                               const float* __restrict__ ad1,
                                               ushort* __restrict__ h1b,
                                               float* __restrict__ al1s,
                                               float* __restrict__ al1d, int N) {
    __shared__ float sB[128 * 64];
    __shared__ float sA[64 * 68];
    const int t = threadIdx.x;
    const int n0 = blockIdx.x * 64;
    {
        const float4* w4 = (const float4*)W1;
        float4* s4 = (float4*)sB;
#pragma unroll
        for (int i = 0; i < 8; ++i) s4[t + i * 256] = w4[t + i * 256];
    }
    const int r0 = (t >> 3) * 2;
    const int c0 = (t & 7) * 8;   // head = t&7, channels c0..c0+7
    float acc0[8] = {0, 0, 0, 0, 0, 0, 0, 0};
    float acc1[8] = {0, 0, 0, 0, 0, 0, 0, 0};
    for (int kb = 0; kb < 2; ++kb) {
        __syncthreads();
#pragma unroll
        for (int i = 0; i < 4; ++i) {
            int idx = t + i * 256;
            int r = idx >> 4, kc = idx & 15;
            int n = n0 + r;
            float4 v = make_float4(0.f, 0.f, 0.f, 0.f);
            if (n < N) v = ((const float4*)x)[(size_t)n * 32 + kb * 16 + kc];
            *(float4*)&sA[r * 68 + kc * 4] = v;
        }
        __syncthreads();
        const float* bptr = &sB[kb * 64 * 64];
#pragma unroll 8
        for (int kk = 0; kk < 64; ++kk) {
            float a0 = sA[r0 * 68 + kk];
            float a1 = sA[(r0 + 1) * 68 + kk];
            const float* bp = &bptr[kk * 64 + c0];
            float4 b0 = *(const float4*)bp;
            float4 b1v = *(const float4*)(bp + 4);
            acc0[0] += a0 * b0.x; acc0[1] += a0 * b0.y; acc0[2] += a0 * b0.z; acc0[3] += a0 * b0.w;
            acc0[4] += a0 * b1v.x; acc0[5] += a0 * b1v.y; acc0[6] += a0 * b1v.z; acc0[7] += a0 * b1v.w;
            acc1[0] += a1 * b0.x; acc1[1] += a1 * b0.y; acc1[2] += a1 * b0.z; acc1[3] += a1 * b0.w;
            acc1[4] += a1 * b1v.x; acc1[5] += a1 * b1v.y; acc1[6] += a1 * b1v.z; acc1[7] += a1 * b1v.w;
        }
    }
    float ps0 = 0.f, pd0 = 0.f, ps1 = 0.f, pd1 = 0.f;
#pragma unroll
    for (int i = 0; i < 8; ++i) {
        float ws = as1[c0 + i], wd = ad1[c0 + i];
        ps0 += acc0[i] * ws; pd0 += acc0[i] * wd;
        ps1 += acc1[i] * ws; pd1 += acc1[i] * wd;
    }
    int n = n0 + r0;
    int head = t & 7;
    if (n < N) {
        uint4 p;
        p.x = (uint)f2bf(acc0[0]) | ((uint)f2bf(acc0[1]) << 16);
        p.y = (uint)f2bf(acc0[2]) | ((uint)f2bf(acc0[3]) << 16);
        p.z = (uint)f2bf(acc0[4]) | ((uint)f2bf(acc0[5]) << 16);
        p.w = (uint)f2bf(acc0[6]) | ((uint)f2bf(acc0[7]) << 16);
        *(uint4*)&h1b[(size_t)n * 64 + c0] = p;
        al1s[(size_t)n * 8 + head] = ps0;
        al1d[(size_t)n * 8 + head] = pd0;
    }
    if (n + 1 < N) {
        uint4 p;
        p.x = (uint)f2bf(acc1[0]) | ((uint)f2bf(acc1[1]) << 16);
        p.y = (uint)f2bf(acc1[2]) | ((uint)f2bf(acc1[3]) << 16);
        p.z = (uint)f2bf(acc1[4]) | ((uint)f2bf(acc1[5]) << 16);
        p.w = (uint)f2bf(acc1[6]) | ((uint)f2bf(acc1[7]) << 16);
        *(uint4*)&h1b[(size_t)(n + 1) * 64 + c0] = p;
        al1s[(size_t)(n + 1) * 8 + head] = ps1;
        al1d[(size_t)(n + 1) * 8 + head] = pd1;
    }
}

// ---- GEMM2: h2b[N,128](bf16) = relu(x1pre+b1) @ W2[64,128], fused al2 ----
__global__ __launch_bounds__(256) void k_gemm2(const float* __restrict__ x1pre,
                                               const float* __restrict__ W2,
                                               const float* __restrict__ b1,
                                               const float* __restrict__ as2,
                                               const float* __restrict__ ad2,
                                               ushort* __restrict__ h2b,
                                               float* __restrict__ al2s,
                                               float* __restrict__ al2d, int N) {
    __shared__ float sB[64 * 128];
    __shared__ float sA[64 * 68];
    const int t = threadIdx.x;
    const int n0 = blockIdx.x * 64;
    {
        const float4* w4 = (const float4*)W2;
        float4* s4 = (float4*)sB;
#pragma unroll
        for (int i = 0; i < 8; ++i) s4[t + i * 256] = w4[t + i * 256];
    }
#pragma unroll
    for (int i = 0; i < 4; ++i) {
        int idx = t + i * 256;
        int r = idx >> 4, kc = idx & 15;
        int n = n0 + r;
        float4 v = make_float4(0.f, 0.f, 0.f, 0.f);
        if (n < N) {
            v = ((const float4*)x1pre)[(size_t)n * 16 + kc];
            float4 bb = ((const float4*)b1)[kc];
            v.x = fmaxf(v.x + bb.x, 0.f);
            v.y = fmaxf(v.y + bb.y, 0.f);
            v.z = fmaxf(v.z + bb.z, 0.f);
            v.w = fmaxf(v.w + bb.w, 0.f);
        }
        *(float4*)&sA[r * 68 + kc * 4] = v;
    }
    __syncthreads();
    const int r0 = (t >> 3) * 2;
    const int cb = (t & 7) * 4;
    float acc0[16], acc1[16];
#pragma unroll
    for (int i = 0; i < 16; ++i) { acc0[i] = 0.f; acc1[i] = 0.f; }
#pragma unroll 4
    for (int k = 0; k < 64; ++k) {
        float a0 = sA[r0 * 68 + k];
        float a1 = sA[(r0 + 1) * 68 + k];
#pragma unroll
        for (int j = 0; j < 4; ++j) {
            float4 b = *(const float4*)&sB[k * 128 + cb + 32 * j];
            acc0[j * 4 + 0] += a0 * b.x; acc0[j * 4 + 1] += a0 * b.y;
            acc0[j * 4 + 2] += a0 * b.z; acc0[j * 4 + 3] += a0 * b.w;
            acc1[j * 4 + 0] += a1 * b.x; acc1[j * 4 + 1] += a1 * b.y;
            acc1[j * 4 + 2] += a1 * b.z; acc1[j * 4 + 3] += a1 * b.w;
        }
    }
    float ps0 = 0.f, pd0 = 0.f, ps1 = 0.f, pd1 = 0.f;
#pragma unroll
    for (int j = 0; j < 4; ++j)
#pragma unroll
        for (int i = 0; i < 4; ++i) {
            int cc = cb + 32 * j + i;
            float ws = as2[cc], wd = ad2[cc];
            ps0 += acc0[j * 4 + i] * ws; pd0 += acc0[j * 4 + i] * wd;
            ps1 += acc1[j * 4 + i] * ws; pd1 += acc1[j * 4 + i] * wd;
        }
#pragma unroll
    for (int off = 1; off < 8; off <<= 1) {
        ps0 += __shfl_xor(ps0, off); pd0 += __shfl_xor(pd0, off);
        ps1 += __shfl_xor(ps1, off); pd1 += __shfl_xor(pd1, off);
    }
    int n = n0 + r0;
    if (n < N) {
#pragma unroll
        for (int j = 0; j < 4; ++j) {
            uint2 q;
            q.x = (uint)f2bf(acc0[j * 4 + 0]) | ((uint)f2bf(acc0[j * 4 + 1]) << 16);
            q.y = (uint)f2bf(acc0[j * 4 + 2]) | ((uint)f2bf(acc0[j * 4 + 3]) << 16);
            *(uint2*)&h2b[(size_t)n * 128 + cb + 32 * j] = q;
        }
        if ((t & 7) == 0) { al2s[n] = ps0; al2d[n] = pd0; }
    }
    if (n + 1 < N) {
#pragma unroll
        for (int j = 0; j < 4; ++j) {
            uint2 q;
            q.x = (uint)f2bf(acc1[j * 4 + 0]) | ((uint)f2bf(acc1[j * 4 + 1]) << 16);
            q.y = (uint)f2bf(acc1[j * 4 + 2]) | ((uint)f2bf(acc1[j * 4 + 3]) << 16);
            *(uint2*)&h2b[(size_t)(n + 1) * 128 + cb + 32 * j] = q;
        }
        if ((t & 7) == 0) { al2s[n + 1] = ps1; al2d[n + 1] = pd1; }
    }
}

// ---------------- CSR construction ----------------
__global__ __launch_bounds__(256) void k_deg(const int* __restrict__ dst,
                                             int* __restrict__ deg,
                                             int* __restrict__ rank, int E) {
    int base = (blockIdx.x * 256 + threadIdx.x) * 4;
    if (base + 4 <= E) {
        int4 d = *(const int4*)&dst[base];
        int r0 = atomicAdd(&deg[d.x], 1);
        int r1 = atomicAdd(&deg[d.y], 1);
        int r2 = atomicAdd(&deg[d.z], 1);
        int r3 = atomicAdd(&deg[d.w], 1);
        *(int4*)&rank[base] = make_int4(r0, r1, r2, r3);
    } else {
        for (int e = base; e < E; ++e) {
            int d = dst[e];
            rank[e] = atomicAdd(&deg[d], 1);
        }
    }
}

__global__ void k_scan1(const int* __restrict__ deg, int* __restrict__ row_ptr,
                        int* __restrict__ bsums, int N) {
    __shared__ int sh[256];
    int t = threadIdx.x, b = blockIdx.x;
    int i = b * 256 + t;
    int v = (i < N) ? (deg[i] + 1) : 0;  // +1 for self-loop
    sh[t] = v;
    __syncthreads();
    int accv = v;
    for (int off = 1; off < 256; off <<= 1) {
        int u = (t >= off) ? sh[t - off] : 0;
        __syncthreads();
        accv += u;
        sh[t] = accv;
        __syncthreads();
    }
    if (i < N) row_ptr[i] = accv - v;
    if (t == 255) bsums[b] = accv;
}

__global__ void k_scan2(int* __restrict__ bsums, int nb) {
    __shared__ int sh[512];
    int t = threadIdx.x;
    int v = (t < nb) ? bsums[t] : 0;
    sh[t] = v;
    __syncthreads();
    int accv = v;
    for (int off = 1; off < 512; off <<= 1) {
        int u = (t >= off) ? sh[t - off] : 0;
        __syncthreads();
        accv += u;
        sh[t] = accv;
        __syncthreads();
    }
    if (t < nb) bsums[t] = accv - v;
}

__global__ void k_scan3(int* __restrict__ row_ptr, const int* __restrict__ bsums,
                        const int* __restrict__ deg, int* __restrict__ col,
                        int N, int total) {
    int i = blockIdx.x * 256 + threadIdx.x;
    if (i < N) {
        int rp = row_ptr[i] + bsums[blockIdx.x];
        row_ptr[i] = rp;
        col[rp + deg[i]] = i;  // self-loop at the end of row i
    }
    if (i == 0) row_ptr[N] = total;
}

__global__ __launch_bounds__(256) void k_fill(const int* __restrict__ src,
                                              const int* __restrict__ dst,
                                              const int* __restrict__ rank,
                                              const int* __restrict__ row_ptr,
                                              int* __restrict__ col, int E) {
    int base = (blockIdx.x * 256 + threadIdx.x) * 4;
    if (base + 4 <= E) {
        int4 d = *(const int4*)&dst[base];
        int4 s = *(const int4*)&src[base];
        int4 r = *(const int4*)&rank[base];
        int p0 = row_ptr[d.x] + r.x;
        int p1 = row_ptr[d.y] + r.y;
        int p2 = row_ptr[d.z] + r.z;
        int p3 = row_ptr[d.w] + r.w;
        col[p0] = s.x;
        col[p1] = s.y;
        col[p2] = s.z;
        col[p3] = s.w;
    } else {
        for (int e = base; e < E; ++e) col[row_ptr[dst[e]] + rank[e]] = src[e];
    }
}

// ---- edge aggregation, layer 1: wave per dst node, two-phase chunked ----
// phase 1 (lane = slot*8+head): lane-parallel weight compute -> LDS
// phase 2 (lane = channel): ds_read w/col + bf16 gather + fma
__global__ __launch_bounds__(256) void k_edge1(const ushort* __restrict__ h1b,
                                               const float* __restrict__ al1s,
                                               const float* __restrict__ al1d,
                                               const int* __restrict__ row_ptr,
                                               const int* __restrict__ col,
                                               float* __restrict__ x1pre, int N) {
    __shared__ float sw[4][64 * 8];   // per-wave: 64 slots x 8 heads
    __shared__ int   scol[4][64];
    const int wid = threadIdx.x >> 6;
    const int node = blockIdx.x * 4 + wid;
    if (node >= N) return;
    const int lane = threadIdx.x & 63;
    const int h = lane & 7;        // phase-1 head
    const int k = lane >> 3;       // phase-1 slot-in-group
    const int c = lane;            // phase-2 channel
    const int hc = lane >> 3;      // phase-2 head for this channel
    float a_d = al1d[(size_t)node * 8 + h];
    const int s0 = row_ptr[node], s1 = row_ptr[node + 1];
    const int deg = s1 - s0;
    float den_part = 0.f;
    float acc = 0.f;
    float* w_lds = sw[wid];
    int* c_lds = scol[wid];
    for (int base = 0; base < deg; base += 64) {
        int chunk = deg - base; if (chunk > 64) chunk = 64;
        // phase 1: 8 edges x 8 heads per pass
        for (int j = 0; j < chunk; j += 8) {
            int slot = j + k;
            bool valid = slot < chunk;
            int cidx = s0 + base + (valid ? slot : 0);
            int colv = col[cidx];
            float e = al1s[(size_t)colv * 8 + h] + a_d;
            e = e > 0.f ? e : 0.2f * e;
            float w = valid ? __expf(e) : 0.f;
            den_part += w;
            w_lds[slot * 8 + h] = w;
            if (h == 0) c_lds[slot] = colv;
        }
        // phase 2: accumulate channels (wave-synchronous LDS, no barrier needed)
        int u = 0;
        for (; u + 4 <= chunk; u += 4) {
            int c0v = c_lds[u], c1v = c_lds[u + 1], c2v = c_lds[u + 2], c3v = c_lds[u + 3];
            float w0 = w_lds[u * 8 + hc],       w1 = w_lds[(u + 1) * 8 + hc];
            float w2 = w_lds[(u + 2) * 8 + hc], w3 = w_lds[(u + 3) * 8 + hc];
            float v0 = bf2f(h1b[(size_t)c0v * 64 + c]);
            float v1 = bf2f(h1b[(size_t)c1v * 64 + c]);
            float v2 = bf2f(h1b[(size_t)c2v * 64 + c]);
            float v3 = bf2f(h1b[(size_t)c3v * 64 + c]);
            acc += w0 * v0 + w1 * v1 + w2 * v2 + w3 * v3;
        }
        for (; u < chunk; ++u) {
            int cv = c_lds[u];
            float w = w_lds[u * 8 + hc];
            acc += w * bf2f(h1b[(size_t)cv * 64 + c]);
        }
    }
    // reduce den over the 8 slot-lanes of each head (lanes differ in bits 3..5)
    den_part += __shfl_xor(den_part, 8);
    den_part += __shfl_xor(den_part, 16);
    den_part += __shfl_xor(den_part, 32);
    // lane hc (k=0, h=hc) holds den for head hc
    float den = __shfl(den_part, hc);
    x1pre[(size_t)node * 64 + c] = acc / den;
}

// ---- edge aggregation, layer 2: wave per node, bf16x2 gather, unroll x8 ----
__global__ __launch_bounds__(256) void k_edge2(const ushort* __restrict__ h2b,
                                               const float* __restrict__ al2s,
                                               const float* __restrict__ al2d,
                                               const int* __restrict__ row_ptr,
                                               const int* __restrict__ col,
                                               const float* __restrict__ b2,
                                               float* __restrict__ x2, int N) {
    int node = blockIdx.x * 4 + (threadIdx.x >> 6);
    if (node >= N) return;
    int c = threadIdx.x & 63;
    float a_d = al2d[node];
    int s0 = row_ptr[node], s1 = row_ptr[node + 1];
    float accx = 0.f, accy = 0.f, den = 0.f;
    const uint* h2u = (const uint*)h2b;  // 64 uints (bf16x2) per row
    for (int base = s0; base < s1; base += 64) {
        int idx = base + c;
        int cidx = idx < s1 ? idx : s1 - 1;
        int my_col = col[cidx];
        float my_e = al2s[my_col] + a_d;
        my_e = my_e > 0.f ? my_e : 0.2f * my_e;
        float my_w = (idx < s1) ? __expf(my_e) : 0.f;
        den += my_w;
        int cnt = s1 - base; if (cnt > 64) cnt = 64;
        int i = 0;
        for (; i + 8 <= cnt; i += 8) {
            int sc[8];
            float wc[8];
            uint uv[8];
#pragma unroll
            for (int u = 0; u < 8; ++u) { sc[u] = __shfl(my_col, i + u); wc[u] = __shfl(my_w, i + u); }
#pragma unroll
            for (int u = 0; u < 8; ++u) uv[u] = h2u[(size_t)sc[u] * 64 + c];
#pragma unroll
            for (int u = 0; u < 8; ++u) {
                float hx = __uint_as_float(uv[u] << 16);
                float hy = __uint_as_float(uv[u] & 0xFFFF0000u);
                accx += wc[u] * hx;
                accy += wc[u] * hy;
            }
        }
        for (; i < cnt; ++i) {
            int sA = __shfl(my_col, i);
            float wA = __shfl(my_w, i);
            uint uv = h2u[(size_t)sA * 64 + c];
            accx += wA * __uint_as_float(uv << 16);
            accy += wA * __uint_as_float(uv & 0xFFFF0000u);
        }
    }
#pragma unroll
    for (int off = 1; off < 64; off <<= 1) den += __shfl_xor(den, off);
    float invd = 1.f / den;
    float2 ob = ((const float2*)b2)[c];
    float2 r;
    r.x = accx * invd + ob.x;
    r.y = accy * invd + ob.y;
    ((float2*)x2)[(size_t)node * 64 + c] = r;
}

// ---- mean pool over sorted batch (run-length chunked atomics) ----
__global__ __launch_bounds__(128) void k_pool(const float* __restrict__ x2,
                                              const int* __restrict__ batch,
                                              float* __restrict__ pooled,
                                              float* __restrict__ cnt, int N) {
    int t = threadIdx.x;
    int nstart = blockIdx.x * 128;
    if (nstart >= N) return;
    int nend = nstart + 128;
    if (nend > N) nend = N;
    float acc = 0.f;
    int cur = batch[nstart];
    int count = 0;
    for (int n = nstart; n < nend; ++n) {
        int g = batch[n];
        if (g != cur) {
            atomicAdd(&pooled[(size_t)cur * 128 + t], acc);
            if (t == 0) atomicAdd(&cnt[cur], (float)count);
            acc = 0.f;
            count = 0;
            cur = g;
        }
        acc += x2[(size_t)n * 128 + t];
        ++count;
    }
    atomicAdd(&pooled[(size_t)cur * 128 + t], acc);
    if (t == 0) atomicAdd(&cnt[cur], (float)count);
}

// ---- FC + log_softmax: one wave per graph ----
__global__ __launch_bounds__(64) void k_fc(const float* __restrict__ pooled,
                                           const float* __restrict__ cnt,
                                           const float* __restrict__ fcw,
                                           const float* __restrict__ fcb,
                                           float* __restrict__ out, int G) {
    int g = blockIdx.x;
    int c = threadIdx.x;
    float2 p = ((const float2*)pooled)[(size_t)g * 64 + c];
    float inv = 1.f / fmaxf(cnt[g], 1.f);
    p.x *= inv; p.y *= inv;
    float l[10];
#pragma unroll
    for (int j = 0; j < 10; ++j)
        l[j] = p.x * fcw[(2 * c) * 10 + j] + p.y * fcw[(2 * c + 1) * 10 + j];
#pragma unroll
    for (int j = 0; j < 10; ++j)
        for (int off = 1; off < 64; off <<= 1) l[j] += __shfl_xor(l[j], off);
    if (c == 0) {
        float lj[10];
        float m = -1e30f;
#pragma unroll
        for (int j = 0; j < 10; ++j) {
            lj[j] = l[j] + fcb[j];
            m = fmaxf(m, lj[j]);
        }
        float s = 0.f;
#pragma unroll
        for (int j = 0; j < 10; ++j) s += expf(lj[j] - m);
        float ls = logf(s);
#pragma unroll
        for (int j = 0; j < 10; ++j) out[(size_t)g * 10 + j] = lj[j] - m - ls;
    }
}

extern "C" void kernel_launch(void* const* d_in, const int* in_sizes, int n_in,
                              void* d_out, int out_size, void* d_ws, size_t ws_size,
                              hipStream_t stream) {
    const float* x     = (const float*)d_in[0];
    const int*   ei    = (const int*)d_in[1];
    const int*   batch = (const int*)d_in[2];
    const float* W1    = (const float*)d_in[3];
    const float* as1   = (const float*)d_in[4];
    const float* ad1   = (const float*)d_in[5];
    const float* b1    = (const float*)d_in[6];
    const float* W2    = (const float*)d_in[7];
    const float* as2   = (const float*)d_in[8];
    const float* ad2   = (const float*)d_in[9];
    const float* b2    = (const float*)d_in[10];
    const float* fcw   = (const float*)d_in[11];
    const float* fcb   = (const float*)d_in[12];
    float* out = (float*)d_out;

    const int N = in_sizes[0] / 128;
    const int E = in_sizes[1] / 2;
    const int G = out_size / 10;
    const int* srcp = ei;
    const int* dstp = ei + E;

    float* wf = (float*)d_ws;
    ushort* h1b   = (ushort*)wf;
    float* x1pre  = wf + (size_t)N * 32;
    float* x2     = wf;
    ushort* h2b   = (ushort*)(wf + (size_t)N * 128);
    float* al1s_  = wf + (size_t)N * 192;
    float* al1d_  = wf + (size_t)N * 200;
    float* al2s_  = wf + (size_t)N * 208;
    float* al2d_  = wf + (size_t)N * 209;
    float* pooled = wf + (size_t)N * 210;
    float* cnt    = pooled + (size_t)G * 128;
    int* deg      = (int*)(cnt + G);             // [N]
    int* row_ptr  = deg + N;                     // [N+1]
    int* col      = row_ptr + N + 1;             // [E+N]
    int* rank     = col + (size_t)E + N;         // [E]
    int* bsums    = rank + E;                    // [<=512]

    size_t zbytes = ((size_t)G * 128 + G + (size_t)N) * sizeof(float);
    hipMemsetAsync(pooled, 0, zbytes, stream);

    const int nb64 = (N + 63) / 64;
    const int nb4  = (N + 3) / 4;
    const int nbS  = (N + 255) / 256;   // <= 512 for k_scan2
    const int nbP  = (N + 127) / 128;
    const int nbE4 = (E + 1023) / 1024; // 4 edges/thread

    k_deg<<<nbE4, 256, 0, stream>>>(dstp, deg, rank, E);
    k_gemm1<<<nb64, 256, 0, stream>>>(x, W1, as1, ad1, h1b, al1s_, al1d_, N);
    k_scan1<<<nbS, 256, 0, stream>>>(deg, row_ptr, bsums, N);
    k_scan2<<<1, 512, 0, stream>>>(bsums, nbS);
    k_scan3<<<nbS, 256, 0, stream>>>(row_ptr, bsums, deg, col, N, E + N);
    k_fill<<<nbE4, 256, 0, stream>>>(srcp, dstp, rank, row_ptr, col, E);
    k_edge1<<<nb4, 256, 0, stream>>>(h1b, al1s_, al1d_, row_ptr, col, x1pre, N);
    k_gemm2<<<nb64, 256, 0, stream>>>(x1pre, W2, b1, as2, ad2, h2b, al2s_, al2d_, N);
    k_edge2<<<nb4, 256, 0, stream>>>(h2b, al2s_, al2d_, row_ptr, col, b2, x2, N);
    k_pool<<<nbP, 128, 0, stream>>>(x2, batch, pooled, cnt, N);
    k_fc<<<G, 64, 0, stream>>>(pooled, cnt, fcw, fcb, out, G);
}

// Round 6
// 452.850 us; speedup vs baseline: 1.0267x; 1.0267x over previous
//
#include <hip/hip_runtime.h>
#include <math.h>

typedef unsigned int uint;
typedef unsigned short ushort;

__device__ inline ushort f2bf(float f) {
    uint u = __float_as_uint(f);
    u += 0x7FFF + ((u >> 16) & 1);  // round-to-nearest-even
    return (ushort)(u >> 16);
}
__device__ inline float bf2f(ushort s) {
    return __uint_as_float(((uint)s) << 16);
}

// ---- GEMM1: h1b[N,64](bf16) = x[N,128] @ W1[128,64], fused al1s/al1d ----
__global__ __launch_bounds__(256) void k_gemm1(const float* __restrict__ x,
                                               const float* __restrict__ W1,
                                               const float* __restrict__ as1,
                                               const float* __restrict__ ad1,
                                               ushort* __restrict__ h1b,
                                               float* __restrict__ al1s,
                                               float* __restrict__ al1d, int N) {
    __shared__ float sB[128 * 64];
    __shared__ float sA[64 * 68];
    const int t = threadIdx.x;
    const int n0 = blockIdx.x * 64;
    {
        const float4* w4 = (const float4*)W1;
        float4* s4 = (float4*)sB;
#pragma unroll
        for (int i = 0; i < 8; ++i) s4[t + i * 256] = w4[t + i * 256];
    }
    const int r0 = (t >> 3) * 2;
    const int c0 = (t & 7) * 8;   // head = t&7, channels c0..c0+7
    float acc0[8] = {0, 0, 0, 0, 0, 0, 0, 0};
    float acc1[8] = {0, 0, 0, 0, 0, 0, 0, 0};
    for (int kb = 0; kb < 2; ++kb) {
        __syncthreads();
#pragma unroll
        for (int i = 0; i < 4; ++i) {
            int idx = t + i * 256;
            int r = idx >> 4, kc = idx & 15;
            int n = n0 + r;
            float4 v = make_float4(0.f, 0.f, 0.f, 0.f);
            if (n < N) v = ((const float4*)x)[(size_t)n * 32 + kb * 16 + kc];
            *(float4*)&sA[r * 68 + kc * 4] = v;
        }
        __syncthreads();
        const float* bptr = &sB[kb * 64 * 64];
#pragma unroll 8
        for (int kk = 0; kk < 64; ++kk) {
            float a0 = sA[r0 * 68 + kk];
            float a1 = sA[(r0 + 1) * 68 + kk];
            const float* bp = &bptr[kk * 64 + c0];
            float4 b0 = *(const float4*)bp;
            float4 b1v = *(const float4*)(bp + 4);
            acc0[0] += a0 * b0.x; acc0[1] += a0 * b0.y; acc0[2] += a0 * b0.z; acc0[3] += a0 * b0.w;
            acc0[4] += a0 * b1v.x; acc0[5] += a0 * b1v.y; acc0[6] += a0 * b1v.z; acc0[7] += a0 * b1v.w;
            acc1[0] += a1 * b0.x; acc1[1] += a1 * b0.y; acc1[2] += a1 * b0.z; acc1[3] += a1 * b0.w;
            acc1[4] += a1 * b1v.x; acc1[5] += a1 * b1v.y; acc1[6] += a1 * b1v.z; acc1[7] += a1 * b1v.w;
        }
    }
    float ps0 = 0.f, pd0 = 0.f, ps1 = 0.f, pd1 = 0.f;
#pragma unroll
    for (int i = 0; i < 8; ++i) {
        float ws = as1[c0 + i], wd = ad1[c0 + i];
        ps0 += acc0[i] * ws; pd0 += acc0[i] * wd;
        ps1 += acc1[i] * ws; pd1 += acc1[i] * wd;
    }
    int n = n0 + r0;
    int head = t & 7;
    if (n < N) {
        uint4 p;
        p.x = (uint)f2bf(acc0[0]) | ((uint)f2bf(acc0[1]) << 16);
        p.y = (uint)f2bf(acc0[2]) | ((uint)f2bf(acc0[3]) << 16);
        p.z = (uint)f2bf(acc0[4]) | ((uint)f2bf(acc0[5]) << 16);
        p.w = (uint)f2bf(acc0[6]) | ((uint)f2bf(acc0[7]) << 16);
        *(uint4*)&h1b[(size_t)n * 64 + c0] = p;
        al1s[(size_t)n * 8 + head] = ps0;
        al1d[(size_t)n * 8 + head] = pd0;
    }
    if (n + 1 < N) {
        uint4 p;
        p.x = (uint)f2bf(acc1[0]) | ((uint)f2bf(acc1[1]) << 16);
        p.y = (uint)f2bf(acc1[2]) | ((uint)f2bf(acc1[3]) << 16);
        p.z = (uint)f2bf(acc1[4]) | ((uint)f2bf(acc1[5]) << 16);
        p.w = (uint)f2bf(acc1[6]) | ((uint)f2bf(acc1[7]) << 16);
        *(uint4*)&h1b[(size_t)(n + 1) * 64 + c0] = p;
        al1s[(size_t)(n + 1) * 8 + head] = ps1;
        al1d[(size_t)(n + 1) * 8 + head] = pd1;
    }
}

// ---- GEMM2: h2b[N,128](bf16) = relu(x1pre+b1) @ W2[64,128], fused al2 ----
__global__ __launch_bounds__(256) void k_gemm2(const float* __restrict__ x1pre,
                                               const float* __restrict__ W2,
                                               const float* __restrict__ b1,
                                               const float* __restrict__ as2,
                                               const float* __restrict__ ad2,
                                               ushort* __restrict__ h2b,
                                               float* __restrict__ al2s,
                                               float* __restrict__ al2d, int N) {
    __shared__ float sB[64 * 128];
    __shared__ float sA[64 * 68];
    const int t = threadIdx.x;
    const int n0 = blockIdx.x * 64;
    {
        const float4* w4 = (const float4*)W2;
        float4* s4 = (float4*)sB;
#pragma unroll
        for (int i = 0; i < 8; ++i) s4[t + i * 256] = w4[t + i * 256];
    }
#pragma unroll
    for (int i = 0; i < 4; ++i) {
        int idx = t + i * 256;
        int r = idx >> 4, kc = idx & 15;
        int n = n0 + r;
        float4 v = make_float4(0.f, 0.f, 0.f, 0.f);
        if (n < N) {
            v = ((const float4*)x1pre)[(size_t)n * 16 + kc];
            float4 bb = ((const float4*)b1)[kc];
            v.x = fmaxf(v.x + bb.x, 0.f);
            v.y = fmaxf(v.y + bb.y, 0.f);
            v.z = fmaxf(v.z + bb.z, 0.f);
            v.w = fmaxf(v.w + bb.w, 0.f);
        }
        *(float4*)&sA[r * 68 + kc * 4] = v;
    }
    __syncthreads();
    const int r0 = (t >> 3) * 2;
    const int cb = (t & 7) * 4;
    float acc0[16], acc1[16];
#pragma unroll
    for (int i = 0; i < 16; ++i) { acc0[i] = 0.f; acc1[i] = 0.f; }
#pragma unroll 4
    for (int k = 0; k < 64; ++k) {
        float a0 = sA[r0 * 68 + k];
        float a1 = sA[(r0 + 1) * 68 + k];
#pragma unroll
        for (int j = 0; j < 4; ++j) {
            float4 b = *(const float4*)&sB[k * 128 + cb + 32 * j];
            acc0[j * 4 + 0] += a0 * b.x; acc0[j * 4 + 1] += a0 * b.y;
            acc0[j * 4 + 2] += a0 * b.z; acc0[j * 4 + 3] += a0 * b.w;
            acc1[j * 4 + 0] += a1 * b.x; acc1[j * 4 + 1] += a1 * b.y;
            acc1[j * 4 + 2] += a1 * b.z; acc1[j * 4 + 3] += a1 * b.w;
        }
    }
    float ps0 = 0.f, pd0 = 0.f, ps1 = 0.f, pd1 = 0.f;
#pragma unroll
    for (int j = 0; j < 4; ++j)
#pragma unroll
        for (int i = 0; i < 4; ++i) {
            int cc = cb + 32 * j + i;
            float ws = as2[cc], wd = ad2[cc];
            ps0 += acc0[j * 4 + i] * ws; pd0 += acc0[j * 4 + i] * wd;
            ps1 += acc1[j * 4 + i] * ws; pd1 += acc1[j * 4 + i] * wd;
        }
#pragma unroll
    for (int off = 1; off < 8; off <<= 1) {
        ps0 += __shfl_xor(ps0, off); pd0 += __shfl_xor(pd0, off);
        ps1 += __shfl_xor(ps1, off); pd1 += __shfl_xor(pd1, off);
    }
    int n = n0 + r0;
    if (n < N) {
#pragma unroll
        for (int j = 0; j < 4; ++j) {
            uint2 q;
            q.x = (uint)f2bf(acc0[j * 4 + 0]) | ((uint)f2bf(acc0[j * 4 + 1]) << 16);
            q.y = (uint)f2bf(acc0[j * 4 + 2]) | ((uint)f2bf(acc0[j * 4 + 3]) << 16);
            *(uint2*)&h2b[(size_t)n * 128 + cb + 32 * j] = q;
        }
        if ((t & 7) == 0) { al2s[n] = ps0; al2d[n] = pd0; }
    }
    if (n + 1 < N) {
#pragma unroll
        for (int j = 0; j < 4; ++j) {
            uint2 q;
            q.x = (uint)f2bf(acc1[j * 4 + 0]) | ((uint)f2bf(acc1[j * 4 + 1]) << 16);
            q.y = (uint)f2bf(acc1[j * 4 + 2]) | ((uint)f2bf(acc1[j * 4 + 3]) << 16);
            *(uint2*)&h2b[(size_t)(n + 1) * 128 + cb + 32 * j] = q;
        }
        if ((t & 7) == 0) { al2s[n + 1] = ps1; al2d[n + 1] = pd1; }
    }
}

// ---------------- CSR construction ----------------
__global__ __launch_bounds__(256) void k_deg(const int* __restrict__ dst,
                                             int* __restrict__ deg,
                                             int* __restrict__ rank, int E) {
    int base = (blockIdx.x * 256 + threadIdx.x) * 4;
    if (base + 4 <= E) {
        int4 d = *(const int4*)&dst[base];
        int r0 = atomicAdd(&deg[d.x], 1);
        int r1 = atomicAdd(&deg[d.y], 1);
        int r2 = atomicAdd(&deg[d.z], 1);
        int r3 = atomicAdd(&deg[d.w], 1);
        *(int4*)&rank[base] = make_int4(r0, r1, r2, r3);
    } else {
        for (int e = base; e < E; ++e) {
            int d = dst[e];
            rank[e] = atomicAdd(&deg[d], 1);
        }
    }
}

__global__ void k_scan1(const int* __restrict__ deg, int* __restrict__ row_ptr,
                        int* __restrict__ bsums, int N) {
    __shared__ int sh[256];
    int t = threadIdx.x, b = blockIdx.x;
    int i = b * 256 + t;
    int v = (i < N) ? (deg[i] + 1) : 0;  // +1 for self-loop
    sh[t] = v;
    __syncthreads();
    int accv = v;
    for (int off = 1; off < 256; off <<= 1) {
        int u = (t >= off) ? sh[t - off] : 0;
        __syncthreads();
        accv += u;
        sh[t] = accv;
        __syncthreads();
    }
    if (i < N) row_ptr[i] = accv - v;
    if (t == 255) bsums[b] = accv;
}

__global__ void k_scan2(int* __restrict__ bsums, int nb) {
    __shared__ int sh[512];
    int t = threadIdx.x;
    int v = (t < nb) ? bsums[t] : 0;
    sh[t] = v;
    __syncthreads();
    int accv = v;
    for (int off = 1; off < 512; off <<= 1) {
        int u = (t >= off) ? sh[t - off] : 0;
        __syncthreads();
        accv += u;
        sh[t] = accv;
        __syncthreads();
    }
    if (t < nb) bsums[t] = accv - v;
}

__global__ void k_scan3(int* __restrict__ row_ptr, const int* __restrict__ bsums,
                        const int* __restrict__ deg, int* __restrict__ col,
                        int N, int total) {
    int i = blockIdx.x * 256 + threadIdx.x;
    if (i < N) {
        int rp = row_ptr[i] + bsums[blockIdx.x];
        row_ptr[i] = rp;
        col[rp + deg[i]] = i;  // self-loop at the end of row i
    }
    if (i == 0) row_ptr[N] = total;
}

__global__ __launch_bounds__(256) void k_fill(const int* __restrict__ src,
                                              const int* __restrict__ dst,
                                              const int* __restrict__ rank,
                                              const int* __restrict__ row_ptr,
                                              int* __restrict__ col, int E) {
    int base = (blockIdx.x * 256 + threadIdx.x) * 4;
    if (base + 4 <= E) {
        int4 d = *(const int4*)&dst[base];
        int4 s = *(const int4*)&src[base];
        int4 r = *(const int4*)&rank[base];
        int p0 = row_ptr[d.x] + r.x;
        int p1 = row_ptr[d.y] + r.y;
        int p2 = row_ptr[d.z] + r.z;
        int p3 = row_ptr[d.w] + r.w;
        col[p0] = s.x;
        col[p1] = s.y;
        col[p2] = s.z;
        col[p3] = s.w;
    } else {
        for (int e = base; e < E; ++e) col[row_ptr[dst[e]] + rank[e]] = src[e];
    }
}

// ---- edge aggregation, layer 1: wave per dst node, two-phase, uint2 loads ----
// phase 1 (lane = slot*8+head): lane-parallel weight compute -> LDS
// phase 2 (16 lanes/edge, 4 edges/pass): uint2 (4ch) gathers
__global__ __launch_bounds__(256) void k_edge1(const ushort* __restrict__ h1b,
                                               const float* __restrict__ al1s,
                                               const float* __restrict__ al1d,
                                               const int* __restrict__ row_ptr,
                                               const int* __restrict__ col,
                                               float* __restrict__ x1pre, int N) {
    __shared__ float sw[4][64 * 8];   // per-wave: 64 slots x 8 heads
    __shared__ int   scol[4][64];
    const int wid = threadIdx.x >> 6;
    const int node = blockIdx.x * 4 + wid;
    if (node >= N) return;
    const int lane = threadIdx.x & 63;
    const int h = lane & 7;        // phase-1 head
    const int k = lane >> 3;       // phase-1 slot-in-group
    const int g2 = lane >> 4;      // phase-2 edge subgroup 0..3
    const int k4 = lane & 15;      // phase-2 channel quad (ch 4k4..4k4+3)
    const int hq = k4 >> 1;        // head of those channels
    float a_d = al1d[(size_t)node * 8 + h];
    const int s0 = row_ptr[node], s1 = row_ptr[node + 1];
    const int deg = s1 - s0;
    float den_part = 0.f;
    float acc4[4] = {0.f, 0.f, 0.f, 0.f};
    float* w_lds = sw[wid];
    int* c_lds = scol[wid];
    const uint2* h1u2 = (const uint2*)h1b;  // 16 uint2 per 64-ch row
    for (int base = 0; base < deg; base += 64) {
        int chunk = deg - base; if (chunk > 64) chunk = 64;
        // phase 1: 8 edges x 8 heads per pass (zero-pads w to mult of 8)
        for (int j = 0; j < chunk; j += 8) {
            int slot = j + k;
            bool valid = slot < chunk;
            int cidx = s0 + base + (valid ? slot : 0);
            int colv = col[cidx];
            float e = al1s[(size_t)colv * 8 + h] + a_d;
            e = e > 0.f ? e : 0.2f * e;
            float w = valid ? __expf(e) : 0.f;
            den_part += w;
            w_lds[slot * 8 + h] = w;
            if (h == 0) c_lds[slot] = colv;
        }
        // phase 2: 4 edges per pass, dual-issued
        int chunkR = (chunk + 3) & ~3;
        int u = 0;
        for (; u + 8 <= chunkR; u += 8) {
            int sA = u + g2, sB = u + 4 + g2;
            int cA = c_lds[sA], cB = c_lds[sB];
            float wA = w_lds[sA * 8 + hq], wB = w_lds[sB * 8 + hq];
            uint2 hA = h1u2[(size_t)cA * 16 + k4];
            uint2 hB = h1u2[(size_t)cB * 16 + k4];
            acc4[0] += wA * __uint_as_float(hA.x << 16);
            acc4[1] += wA * __uint_as_float(hA.x & 0xFFFF0000u);
            acc4[2] += wA * __uint_as_float(hA.y << 16);
            acc4[3] += wA * __uint_as_float(hA.y & 0xFFFF0000u);
            acc4[0] += wB * __uint_as_float(hB.x << 16);
            acc4[1] += wB * __uint_as_float(hB.x & 0xFFFF0000u);
            acc4[2] += wB * __uint_as_float(hB.y << 16);
            acc4[3] += wB * __uint_as_float(hB.y & 0xFFFF0000u);
        }
        if (u < chunkR) {
            int sA = u + g2;
            int cA = c_lds[sA];
            float wA = w_lds[sA * 8 + hq];
            uint2 hA = h1u2[(size_t)cA * 16 + k4];
            acc4[0] += wA * __uint_as_float(hA.x << 16);
            acc4[1] += wA * __uint_as_float(hA.x & 0xFFFF0000u);
            acc4[2] += wA * __uint_as_float(hA.y << 16);
            acc4[3] += wA * __uint_as_float(hA.y & 0xFFFF0000u);
        }
    }
    // reduce acc over the 4 edge subgroups (lane bits 4..5)
#pragma unroll
    for (int i = 0; i < 4; ++i) {
        acc4[i] += __shfl_xor(acc4[i], 16);
        acc4[i] += __shfl_xor(acc4[i], 32);
    }
    // den per head: reduce over slot-lanes (bits 3..5); lane h holds head h
    den_part += __shfl_xor(den_part, 8);
    den_part += __shfl_xor(den_part, 16);
    den_part += __shfl_xor(den_part, 32);
    float den = __shfl(den_part, hq);
    if (lane < 16) {
        float invd = 1.f / den;
        float4 o = make_float4(acc4[0] * invd, acc4[1] * invd, acc4[2] * invd, acc4[3] * invd);
        ((float4*)x1pre)[(size_t)node * 16 + k4] = o;
    }
}

// ---- edge aggregation, layer 2: wave per node, uint2 loads, 2 edges/pass ----
__global__ __launch_bounds__(256) void k_edge2(const ushort* __restrict__ h2b,
                                               const float* __restrict__ al2s,
                                               const float* __restrict__ al2d,
                                               const int* __restrict__ row_ptr,
                                               const int* __restrict__ col,
                                               const float* __restrict__ b2,
                                               float* __restrict__ x2, int N) {
    int node = blockIdx.x * 4 + (threadIdx.x >> 6);
    if (node >= N) return;
    const int lane = threadIdx.x & 63;
    const int g2 = lane >> 5;   // edge subgroup 0..1
    const int k4 = lane & 31;   // channel quad (ch 4k4..4k4+3 of 128)
    float a_d = al2d[node];
    int s0 = row_ptr[node], s1 = row_ptr[node + 1];
    float acc4[4] = {0.f, 0.f, 0.f, 0.f};
    float den = 0.f;
    const uint2* h2u2 = (const uint2*)h2b;  // 32 uint2 per 128-ch row
    for (int base = s0; base < s1; base += 64) {
        int idx = base + lane;
        int cidx = idx < s1 ? idx : s1 - 1;
        int my_col = col[cidx];
        float my_e = al2s[my_col] + a_d;
        my_e = my_e > 0.f ? my_e : 0.2f * my_e;
        float my_w = (idx < s1) ? __expf(my_e) : 0.f;
        den += my_w;
        int cnt = s1 - base; if (cnt > 64) cnt = 64;
        int cntR = (cnt + 1) & ~1;   // shfl at index cnt gives w=0, col clamped
        int i = 0;
        for (; i + 4 <= cntR; i += 4) {
            int eA = i + g2, eB = i + 2 + g2;
            int cA = __shfl(my_col, eA), cB = __shfl(my_col, eB);
            float wA = __shfl(my_w, eA), wB = __shfl(my_w, eB);
            uint2 hA = h2u2[(size_t)cA * 32 + k4];
            uint2 hB = h2u2[(size_t)cB * 32 + k4];
            acc4[0] += wA * __uint_as_float(hA.x << 16);
            acc4[1] += wA * __uint_as_float(hA.x & 0xFFFF0000u);
            acc4[2] += wA * __uint_as_float(hA.y << 16);
            acc4[3] += wA * __uint_as_float(hA.y & 0xFFFF0000u);
            acc4[0] += wB * __uint_as_float(hB.x << 16);
            acc4[1] += wB * __uint_as_float(hB.x & 0xFFFF0000u);
            acc4[2] += wB * __uint_as_float(hB.y << 16);
            acc4[3] += wB * __uint_as_float(hB.y & 0xFFFF0000u);
        }
        if (i < cntR) {
            int eA = i + g2;
            int cA = __shfl(my_col, eA);
            float wA = __shfl(my_w, eA);
            uint2 hA = h2u2[(size_t)cA * 32 + k4];
            acc4[0] += wA * __uint_as_float(hA.x << 16);
            acc4[1] += wA * __uint_as_float(hA.x & 0xFFFF0000u);
            acc4[2] += wA * __uint_as_float(hA.y << 16);
            acc4[3] += wA * __uint_as_float(hA.y & 0xFFFF0000u);
        }
    }
#pragma unroll
    for (int off = 1; off < 64; off <<= 1) den += __shfl_xor(den, off);
#pragma unroll
    for (int i = 0; i < 4; ++i) acc4[i] += __shfl_xor(acc4[i], 32);
    if (lane < 32) {
        float invd = 1.f / den;
        float4 ob = ((const float4*)b2)[k4];
        float4 r;
        r.x = acc4[0] * invd + ob.x;
        r.y = acc4[1] * invd + ob.y;
        r.z = acc4[2] * invd + ob.z;
        r.w = acc4[3] * invd + ob.w;
        ((float4*)x2)[(size_t)node * 32 + k4] = r;
    }
}

// ---- mean pool over sorted batch (run-length chunked atomics) ----
__global__ __launch_bounds__(128) void k_pool(const float* __restrict__ x2,
                                              const int* __restrict__ batch,
                                              float* __restrict__ pooled,
                                              float* __restrict__ cnt, int N) {
    int t = threadIdx.x;
    int nstart = blockIdx.x * 128;
    if (nstart >= N) return;
    int nend = nstart + 128;
    if (nend > N) nend = N;
    float acc = 0.f;
    int cur = batch[nstart];
    int count = 0;
    for (int n = nstart; n < nend; ++n) {
        int g = batch[n];
        if (g != cur) {
            atomicAdd(&pooled[(size_t)cur * 128 + t], acc);
            if (t == 0) atomicAdd(&cnt[cur], (float)count);
            acc = 0.f;
            count = 0;
            cur = g;
        }
        acc += x2[(size_t)n * 128 + t];
        ++count;
    }
    atomicAdd(&pooled[(size_t)cur * 128 + t], acc);
    if (t == 0) atomicAdd(&cnt[cur], (float)count);
}

// ---- FC + log_softmax: one wave per graph ----
__global__ __launch_bounds__(64) void k_fc(const float* __restrict__ pooled,
                                           const float* __restrict__ cnt,
                                           const float* __restrict__ fcw,
                                           const float* __restrict__ fcb,
                                           float* __restrict__ out, int G) {
    int g = blockIdx.x;
    int c = threadIdx.x;
    float2 p = ((const float2*)pooled)[(size_t)g * 64 + c];
    float inv = 1.f / fmaxf(cnt[g], 1.f);
    p.x *= inv; p.y *= inv;
    float l[10];
#pragma unroll
    for (int j = 0; j < 10; ++j)
        l[j] = p.x * fcw[(2 * c) * 10 + j] + p.y * fcw[(2 * c + 1) * 10 + j];
#pragma unroll
    for (int j = 0; j < 10; ++j)
        for (int off = 1; off < 64; off <<= 1) l[j] += __shfl_xor(l[j], off);
    if (c == 0) {
        float lj[10];
        float m = -1e30f;
#pragma unroll
        for (int j = 0; j < 10; ++j) {
            lj[j] = l[j] + fcb[j];
            m = fmaxf(m, lj[j]);
        }
        float s = 0.f;
#pragma unroll
        for (int j = 0; j < 10; ++j) s += expf(lj[j] - m);
        float ls = logf(s);
#pragma unroll
        for (int j = 0; j < 10; ++j) out[(size_t)g * 10 + j] = lj[j] - m - ls;
    }
}

extern "C" void kernel_launch(void* const* d_in, const int* in_sizes, int n_in,
                              void* d_out, int out_size, void* d_ws, size_t ws_size,
                              hipStream_t stream) {
    const float* x     = (const float*)d_in[0];
    const int*   ei    = (const int*)d_in[1];
    const int*   batch = (const int*)d_in[2];
    const float* W1    = (const float*)d_in[3];
    const float* as1   = (const float*)d_in[4];
    const float* ad1   = (const float*)d_in[5];
    const float* b1    = (const float*)d_in[6];
    const float* W2    = (const float*)d_in[7];
    const float* as2   = (const float*)d_in[8];
    const float* ad2   = (const float*)d_in[9];
    const float* b2    = (const float*)d_in[10];
    const float* fcw   = (const float*)d_in[11];
    const float* fcb   = (const float*)d_in[12];
    float* out = (float*)d_out;

    const int N = in_sizes[0] / 128;
    const int E = in_sizes[1] / 2;
    const int G = out_size / 10;
    const int* srcp = ei;
    const int* dstp = ei + E;

    float* wf = (float*)d_ws;
    ushort* h1b   = (ushort*)wf;
    float* x1pre  = wf + (size_t)N * 32;
    float* x2     = wf;
    ushort* h2b   = (ushort*)(wf + (size_t)N * 128);
    float* al1s_  = wf + (size_t)N * 192;
    float* al1d_  = wf + (size_t)N * 200;
    float* al2s_  = wf + (size_t)N * 208;
    float* al2d_  = wf + (size_t)N * 209;
    float* pooled = wf + (size_t)N * 210;
    float* cnt    = pooled + (size_t)G * 128;
    int* deg      = (int*)(cnt + G);             // [N]
    int* row_ptr  = deg + N;                     // [N+1]
    int* col      = row_ptr + N + 1;             // [E+N]
    int* rank     = col + (size_t)E + N;         // [E]
    int* bsums    = rank + E;                    // [<=512]

    size_t zbytes = ((size_t)G * 128 + G + (size_t)N) * sizeof(float);
    hipMemsetAsync(pooled, 0, zbytes, stream);

    const int nb64 = (N + 63) / 64;
    const int nb4  = (N + 3) / 4;
    const int nbS  = (N + 255) / 256;   // <= 512 for k_scan2
    const int nbP  = (N + 127) / 128;
    const int nbE4 = (E + 1023) / 1024; // 4 edges/thread

    k_deg<<<nbE4, 256, 0, stream>>>(dstp, deg, rank, E);
    k_gemm1<<<nb64, 256, 0, stream>>>(x, W1, as1, ad1, h1b, al1s_, al1d_, N);
    k_scan1<<<nbS, 256, 0, stream>>>(deg, row_ptr, bsums, N);
    k_scan2<<<1, 512, 0, stream>>>(bsums, nbS);
    k_scan3<<<nbS, 256, 0, stream>>>(row_ptr, bsums, deg, col, N, E + N);
    k_fill<<<nbE4, 256, 0, stream>>>(srcp, dstp, rank, row_ptr, col, E);
    k_edge1<<<nb4, 256, 0, stream>>>(h1b, al1s_, al1d_, row_ptr, col, x1pre, N);
    k_gemm2<<<nb64, 256, 0, stream>>>(x1pre, W2, b1, as2, ad2, h2b, al2s_, al2d_, N);
    k_edge2<<<nb4, 256, 0, stream>>>(h2b, al2s_, al2d_, row_ptr, col, b2, x2, N);
    k_pool<<<nbP, 128, 0, stream>>>(x2, batch, pooled, cnt, N);
    k_fc<<<G, 64, 0, stream>>>(pooled, cnt, fcw, fcb, out, G);
}